// Round 13
// baseline (1485.328 us; speedup 1.0000x reference)
//
#include <hip/hip_runtime.h>
#include <math.h>

constexpr int VOX = 128 * 128 * 128;     // 2,097,152
constexpr int NPIX = 16 * 128 * 128;     // 262,144
constexpr int NS = 16;
constexpr float RES_RATIO = 1.5f;
constexpr int CSTR = 128;
// a_kernel LDS tile dims (provable bounds: x,y extent <= 18.1, z <= 8.1)
constexpr int TNX = 19, TNY = 19, TNZ = 10;

// Per-slice constant block (floats, stride 128):
//  [0..11]  T row-major  [12..14] tc=t+63.5  [15..17] col L1 norms
//  [18..20] row L1 norms [21..22] z slab     [24+3k..] rotated PSF offsets
// Globals at cst+NS*CSTR: separable psf fx[3],fy[3],fz[3] (1/c^2 in fz)

__global__ __launch_bounds__(512) void prep_kernel(
    const float* __restrict__ theta, const float* __restrict__ psf,
    float* __restrict__ cst, int* __restrict__ zb)
{
    int tid = threadIdx.x;
    int n = tid >> 5, j = tid & 31;
    if (n < NS) {
        const float* T = theta + n * 12;
        float* C = cst + n * CSTR;
        if (j < 12) C[j] = T[j];
        if (j == 12) {
            float r00=T[0], r01=T[1], r02=T[2],  t0=T[3];
            float r10=T[4], r11=T[5], r12=T[6],  t1=T[7];
            float r20=T[8], r21=T[9], r22=T[10], t2=T[11];
            float tc0 = t0 + 63.5f, tc1 = t1 + 63.5f, tc2 = t2 + 63.5f;
            C[12]=tc0; C[13]=tc1; C[14]=tc2;
            float C2 = fabsf(r02)+fabsf(r12)+fabsf(r22);
            C[15] = fabsf(r00)+fabsf(r10)+fabsf(r20);
            C[16] = fabsf(r01)+fabsf(r11)+fabsf(r21);
            C[17] = C2;
            C[18] = fabsf(r00)+fabsf(r01)+fabsf(r02);
            C[19] = fabsf(r10)+fabsf(r11)+fabsf(r12);
            C[20] = fabsf(r20)+fabsf(r21)+fabsf(r22);
            float mx = fmaxf(tc0, 127.0f - tc0);
            float my = fmaxf(tc1, 127.0f - tc1);
            float marg = 1.0f + C2 + fabsf(r02)*mx + fabsf(r12)*my;
            float inv = 1.0f / fabsf(r22);
            C[21] = tc2 - marg * inv;
            C[22] = tc2 + marg * inv;
        }
        if (j < 27) {
            float ox = (float)(j % 3) - 1.0f;
            float oy = (float)((j / 3) % 3) - 1.0f;
            float oz = (float)(j / 9) - 1.0f;
            C[24 + 3*j + 0] = T[0]*ox + T[1]*oy + T[2]*oz;
            C[24 + 3*j + 1] = T[4]*ox + T[5]*oy + T[6]*oz;
            C[24 + 3*j + 2] = T[8]*ox + T[9]*oy + T[10]*oz;
        }
    }
    __syncthreads();
    if (tid == 0) {
        float zmin = 1e30f, zmax = -1e30f;
        for (int s = 0; s < NS; ++s) {
            zmin = fminf(zmin, cst[s * CSTR + 21]);
            zmax = fmaxf(zmax, cst[s * CSTR + 22]);
        }
        zb[0] = max(0, (int)floorf(zmin));
        zb[1] = min(127, (int)ceilf(zmax));
        float* G = cst + NS * CSTR;
        float c = psf[13];
        float ic2 = 1.0f / (c * c);
        G[0]=psf[12]; G[1]=psf[13]; G[2]=psf[14];
        G[3]=psf[10]; G[4]=psf[13]; G[5]=psf[16];
        G[6]=psf[4]*ic2; G[7]=psf[13]*ic2; G[8]=psf[22]*ic2;
    }
}

// ---------------------------------------------------------------------------
// Reductions: 64 spread slots (stride 32 doubles). Contain __syncthreads():
// every thread of the block MUST reach them (no wave-divergent early returns).
// ---------------------------------------------------------------------------
__device__ __forceinline__ void block_reduce_spread(double s, double* slots)
{
    #pragma unroll
    for (int off = 32; off > 0; off >>= 1)
        s += __shfl_down(s, off, 64);
    __shared__ double ls[4];
    if ((threadIdx.x & 63) == 0) ls[threadIdx.x >> 6] = s;
    __syncthreads();
    if (threadIdx.x == 0)
        atomicAdd(&slots[(blockIdx.x & 63) * 32], ls[0] + ls[1] + ls[2] + ls[3]);
}

__device__ __forceinline__ void block_reduce3(
    double s0, double s1, double s2, double* a0, double* a1, double* a2)
{
    #pragma unroll
    for (int off = 32; off > 0; off >>= 1) {
        s0 += __shfl_down(s0, off, 64);
        s1 += __shfl_down(s1, off, 64);
        s2 += __shfl_down(s2, off, 64);
    }
    __shared__ double ls3[12];
    int wid = threadIdx.x >> 6;
    if ((threadIdx.x & 63) == 0) {
        ls3[wid*3+0] = s0; ls3[wid*3+1] = s1; ls3[wid*3+2] = s2;
    }
    __syncthreads();
    if (threadIdx.x == 0) {
        int sl = (blockIdx.x & 63) * 32;
        atomicAdd(&a0[sl], ls3[0]+ls3[3]+ls3[6]+ls3[9]);
        atomicAdd(&a1[sl], ls3[1]+ls3[4]+ls3[7]+ls3[10]);
        atomicAdd(&a2[sl], ls3[2]+ls3[5]+ls3[8]+ls3[11]);
    }
}

// ---------------------------------------------------------------------------
// A: PSF-weighted trilinear gather, LDS-tiled (64-thread blocks, 8x8 patch).
// If subsrc != null: out = subsrc - A(vol)   (for r0 = At(slices - A x0)).
// Block 0 zeroes the next reduction-slot arrays.
// ---------------------------------------------------------------------------
__global__ __launch_bounds__(64) void a_kernel(
    const float* __restrict__ cst, const float* __restrict__ vol,
    const float* __restrict__ psf, float* __restrict__ out,
    const float* __restrict__ subsrc,
    double* __restrict__ z1, double* __restrict__ z2, double* __restrict__ z3)
{
    int tid = threadIdx.x;
    if (blockIdx.x == 0) {
        for (int i = tid; i < 2048; i += 64) {
            if (z1) z1[i] = 0.0;
            if (z2) z2[i] = 0.0;
            if (z3) z3[i] = 0.0;
        }
    }

    int b = blockIdx.x;              // 4096 blocks: n = b>>8, patch = b&255
    int n = b >> 8;
    int pb = b & 255;
    int w0 = (pb & 15) << 3, h0 = (pb >> 4) << 3;
    int w = w0 + (tid & 7), h = h0 + (tid >> 3);
    int oidx = (n << 14) + (h << 7) + w;
    float base = subsrc ? subsrc[oidx] : 0.0f;
    float sgn = subsrc ? -1.0f : 1.0f;

    const float* C = cst + n * CSTR;
    float r00=C[0], r01=C[1];
    float r10=C[4], r11=C[5];
    float r20=C[8], r21=C[9];

    float uc = (w0 + 3.5f - 63.5f) * RES_RATIO;
    float vc = (h0 + 3.5f - 63.5f) * RES_RATIO;
    const float du = 5.25f, dv = 5.25f;
    float cx = r00*uc + r01*vc + C[12];
    float cy = r10*uc + r11*vc + C[13];
    float cz = r20*uc + r21*vc + C[14];
    float hx = fabsf(r00)*du + fabsf(r01)*dv + C[18];
    float hy = fabsf(r10)*du + fabsf(r11)*dv + C[19];
    float hz = fabsf(r20)*du + fabsf(r21)*dv + C[20];
    int tx0 = (int)floorf(cx - hx);
    int ty0 = (int)floorf(cy - hy);
    int tz0 = (int)floorf(cz - hz);

    if (tx0 >= 128 || tx0 + TNX <= 0 || ty0 >= 128 || ty0 + TNY <= 0 ||
        tz0 >= 128 || tz0 + TNZ <= 0) {
        out[oidx] = base;
        return;
    }

    __shared__ float tile[TNZ * TNY * TNX];
    for (int i = tid; i < TNZ * TNY * TNX; i += 64) {
        int xx = i % TNX; int rem = i / TNX;
        int yy = rem % TNY; int zz = rem / TNY;
        int gx = tx0 + xx, gy = ty0 + yy, gz = tz0 + zz;
        bool ok = ((unsigned)gx < 128u) & ((unsigned)gy < 128u) & ((unsigned)gz < 128u);
        int off = ok ? ((gz << 14) + (gy << 7) + gx) : 0;
        float v = vol[off];
        tile[i] = ok ? v : 0.0f;
    }
    __syncthreads();

    float u = (w - 63.5f) * RES_RATIO;
    float v = (h - 63.5f) * RES_RATIO;
    float px = fmaf(r00, u, fmaf(r01, v, C[12])) - (float)tx0;
    float py = fmaf(r10, u, fmaf(r11, v, C[13])) - (float)ty0;
    float pz = fmaf(r20, u, fmaf(r21, v, C[14])) - (float)tz0;

    const float* O = C + 24;
    float acc = 0.0f;
    for (int k = 0; k < 27; ++k) {
        float sx = px + O[3*k+0];
        float sy = py + O[3*k+1];
        float sz = pz + O[3*k+2];
        int x0 = (int)sx, y0 = (int)sy, z0 = (int)sz;
        float fx = sx - (float)x0, fy = sy - (float)y0, fz = sz - (float)z0;
        const float* tp = tile + (z0 * TNY + y0) * TNX + x0;
        float c000 = tp[0],             c001 = tp[1];
        float c010 = tp[TNX],           c011 = tp[TNX+1];
        float c100 = tp[TNY*TNX],       c101 = tp[TNY*TNX+1];
        float c110 = tp[TNY*TNX+TNX],   c111 = tp[TNY*TNX+TNX+1];
        float c00 = fmaf(fx, c001 - c000, c000);
        float c01 = fmaf(fx, c011 - c010, c010);
        float c10 = fmaf(fx, c101 - c100, c100);
        float c11 = fmaf(fx, c111 - c110, c110);
        float c0  = fmaf(fy, c01 - c00, c00);
        float c1  = fmaf(fy, c11 - c10, c10);
        acc = fmaf(psf[k], fmaf(fz, c1 - c0, c0), acc);
    }
    out[oidx] = fmaf(sgn, acc, base);
}

// ---------------------------------------------------------------------------
// Per-(voxel, slice) At contribution: shifted-lattice 5x5 window with
// 3-term z evaluation. Weights self-zero outside the true support (clamped),
// including the |oz - gpz| >= C2 case — callers may invoke this for
// half-dead voxels and get exact 0 (L1-bound predication argument).
// ---------------------------------------------------------------------------
__device__ __forceinline__ float at_vox(
    float gx, float gy, float gz, float gpx, float gpy,
    float r00, float r01, float r02,
    float r10, float r11, float r12,
    float r20, float r21, float r22,
    float C0, float C1,
    const float* __restrict__ slice_n,
    float pfx0, float pfx1, float pfx2,
    float pfy0, float pfy1, float pfy2,
    float pfz0, float pfz1, float pfz2)
{
    float gpx2 = gpx + 95.25f;
    float gpy2 = gpy + 95.25f;
    int m2 = (int)floorf(2.0f * (gpx2 - C0)) + 601;
    int n2 = (int)floorf(2.0f * (gpy2 - C1)) + 601;
    int wb = m2 / 3;
    int hb = n2 / 3;

    float s[3][3];
    #pragma unroll
    for (int a = 0; a < 3; ++a) {
        int hv = hb - 200 + a;
        bool hok = ((unsigned)hv < 128u);
        #pragma unroll
        for (int c = 0; c < 3; ++c) {
            int wv = wb - 200 + c;
            bool ok = hok & ((unsigned)wv < 128u);
            int off = ok ? ((hv << 7) + wv) : 0;
            float vs = slice_n[off];
            s[a][c] = ok ? vs : 0.0f;
        }
    }

    float fxv[5], col0[5], col1[5], col2[5], Axa[5], Aya[5], Aza[5];
    #pragma unroll
    for (int i = 0; i < 5; ++i) {
        int m = m2 + i;
        int ki = m - (m / 3) * 3;
        int twoj = (ki == 0) ? 0 : ((ki == 1) ? -2 : 2);
        int wi = (m - twoj) / 3;
        int dwi = wi - wb;
        fxv[i] = (ki == 0) ? pfx1 : ((ki == 1) ? pfx0 : pfx2);
        col0[i] = (dwi == 0) ? s[0][0] : ((dwi == 1) ? s[0][1] : s[0][2]);
        col1[i] = (dwi == 0) ? s[1][0] : ((dwi == 1) ? s[1][1] : s[1][2]);
        col2[i] = (dwi == 0) ? s[2][0] : ((dwi == 1) ? s[2][1] : s[2][2]);
        float mu = 0.5f * (float)(m - 600) - 95.25f;
        Axa[i] = fmaf(r00, mu, -gx);
        Aya[i] = fmaf(r10, mu, -gy);
        Aza[i] = fmaf(r20, mu, -gz);
    }
    float fyv[5], mvv[5];
    int dhj[5];
    #pragma unroll
    for (int j = 0; j < 5; ++j) {
        int m = n2 + j;
        int kj = m - (m / 3) * 3;
        int twoj = (kj == 0) ? 0 : ((kj == 1) ? -2 : 2);
        int hj = (m - twoj) / 3;
        dhj[j] = hj - hb;
        fyv[j] = (kj == 0) ? pfy1 : ((kj == 1) ? pfy0 : pfy2);
        mvv[j] = 0.5f * (float)(m - 600) - 95.25f;
    }

    float acc0 = 0.0f, acc1 = 0.0f;
    #pragma unroll
    for (int i = 0; i < 5; ++i) {
        #pragma unroll
        for (int j = 0; j < 5; ++j) {
            float sval = (dhj[j] == 0) ? col0[i]
                       : ((dhj[j] == 1) ? col1[i] : col2[i]);
            float svf = sval * fxv[i] * fyv[j];
            float Bx = fmaf(r01, mvv[j], Axa[i]);
            float By = fmaf(r11, mvv[j], Aya[i]);
            float Bz = fmaf(r21, mvv[j], Aza[i]);
            float w0 = fmaxf(1.0f - fabsf(Bx - r02), 0.0f)
                     * fmaxf(1.0f - fabsf(By - r12), 0.0f)
                     * fmaxf(1.0f - fabsf(Bz - r22), 0.0f);
            float w1 = fmaxf(1.0f - fabsf(Bx), 0.0f)
                     * fmaxf(1.0f - fabsf(By), 0.0f)
                     * fmaxf(1.0f - fabsf(Bz), 0.0f);
            float w2 = fmaxf(1.0f - fabsf(Bx + r02), 0.0f)
                     * fmaxf(1.0f - fabsf(By + r12), 0.0f)
                     * fmaxf(1.0f - fabsf(Bz + r22), 0.0f);
            float t = fmaf(w0, pfz0, fmaf(w1, pfz1, w2 * pfz2));
            if (i & 1) acc1 = fmaf(t, svf, acc1);
            else       acc0 = fmaf(t, svf, acc0);
        }
    }
    return acc0 + acc1;
}

// ---------------------------------------------------------------------------
// At as GATHER: each thread handles a z-PAIR of voxels (z, z+1) — slice
// constants, ballot, and geometry amortized over 2 voxels; 18 independent
// sval loads in flight; two independent FMA chains. Blocks = 16x16x2 tiles
// (waves = 8x8 patches). NO wave-divergent early return before the tail
// reductions (r11 failure mode); dead waves fall through with acc=0.
// Modes (uniform): init_rp: r=p=acc, reduce acc^2;
//                  else:    vol=acc, reduce {acc*dvec, acc*rvec, acc*acc}.
// ---------------------------------------------------------------------------
__global__ __launch_bounds__(256, 4) void at_gather_kernel(
    const float* __restrict__ cst, const int* __restrict__ zb,
    const float* __restrict__ sl, float* __restrict__ vol,
    const float* __restrict__ dvec, const float* __restrict__ rvec,
    double* __restrict__ s_pap, double* __restrict__ s_rap, double* __restrict__ s_apap,
    int init_rp, float* __restrict__ rv, float* __restrict__ pv)
{
    int b = blockIdx.x;
    int z0i = (b >> 6) << 1;                 // even z of the pair
    if (z0i + 1 < zb[0] || z0i > zb[1]) return;   // block-uniform: safe

    int tid = threadIdx.x;
    int lane = tid & 63, quad = tid >> 6;
    int tx = (b & 7) << 4, ty = ((b >> 3) & 7) << 4;
    int wpx = tx + ((quad & 1) << 3);        // wave patch origin (8x8)
    int wpy = ty + ((quad >> 1) << 3);
    int x = wpx + (lane & 7);
    int y = wpy + (lane >> 3);
    float qx = (float)x, qy = (float)y, qzA = (float)z0i;

    // per-wave slice mask via ballot: lane i<16 tests slice i on this patch
    // (center at z+0.5, half-extents 3.5,3.5,0.5)
    bool cond = false;
    if (lane < NS) {
        const float* C = cst + lane * CSTR;
        float gx = (float)wpx + 3.5f - C[12];
        float gy = (float)wpy + 3.5f - C[13];
        float gz = qzA + 0.5f - C[14];
        float gpz = C[2]*gx + C[6]*gy + C[10]*gz;
        float margin = (fabsf(C[2]) + fabsf(C[6])) * 3.5f + fabsf(C[10]) * 0.5f;
        cond = fabsf(gpz) < 1.0f + C[17] + margin;
    }
    unsigned mask = (unsigned)(__ballot(cond) & 0xFFFFull);

    int idxA = (z0i << 14) + (y << 7) + x;
    int idxB = idxA + (1 << 14);

    const float* G = cst + NS * CSTR;
    float pfx0=G[0], pfx1=G[1], pfx2=G[2];
    float pfy0=G[3], pfy1=G[4], pfy2=G[5];
    float pfz0=G[6], pfz1=G[7], pfz2=G[8];

    float accA = 0.0f, accB = 0.0f;
    while (mask) {
        int n = __ffs(mask) - 1;
        mask &= mask - 1;
        n = __builtin_amdgcn_readfirstlane(n);   // wave-uniform: scalarize C loads
        const float* C = cst + n * CSTR;
        float r00=C[0], r01=C[1], r02=C[2];
        float r10=C[4], r11=C[5], r12=C[6];
        float r20=C[8], r21=C[9], r22=C[10];
        float gx = qx - C[12], gy = qy - C[13], gzA = qzA - C[14];
        float C0 = C[15], C1 = C[16], C2 = C[17];

        float gpzA = r02*gx + r12*gy + r22*gzA;
        float gpzB = gpzA + r22;
        float lim = 1.0f + C2;
        if (fabsf(gpzA) >= lim && fabsf(gpzB) >= lim) continue;  // both dead
        float gpxA = r00*gx + r10*gy + r20*gzA;
        float gpyA = r01*gx + r11*gy + r21*gzA;
        float gpxB = gpxA + r20;
        float gpyB = gpyA + r21;

        const float* slice_n = sl + (n << 14);
        accA += at_vox(gx, gy, gzA,        gpxA, gpyA,
                       r00,r01,r02, r10,r11,r12, r20,r21,r22, C0, C1, slice_n,
                       pfx0,pfx1,pfx2, pfy0,pfy1,pfy2, pfz0,pfz1,pfz2);
        accB += at_vox(gx, gy, gzA + 1.0f, gpxB, gpyB,
                       r00,r01,r02, r10,r11,r12, r20,r21,r22, C0, C1, slice_n,
                       pfx0,pfx1,pfx2, pfy0,pfy1,pfy2, pfz0,pfz1,pfz2);
    }

    if (init_rp) {       // r = p = At(slices - A x0); rr0 += r^2
        rv[idxA] = accA; pv[idxA] = accA;
        rv[idxB] = accB; pv[idxB] = accB;
        block_reduce_spread((double)accA * (double)accA
                          + (double)accB * (double)accB, s_pap);
    } else {
        vol[idxA] = accA;
        vol[idxB] = accB;
        double a = (double)accA, c = (double)accB;
        block_reduce3(a * (double)dvec[idxA] + c * (double)dvec[idxB],
                      a * (double)rvec[idxA] + c * (double)rvec[idxB],
                      a * a + c * c,
                      s_pap, s_rap, s_apap);
    }
}

// ---------------------------------------------------------------------------
// Merged CG update: alpha = rr_old/pAp; rr_new = rr_old - 2a*rAp + a^2*ApAp;
// beta = rr_new/rr_old; x += a p; r -= a Ap; p = r + beta p.
// ---------------------------------------------------------------------------
__global__ __launch_bounds__(256) void update_kernel(
    float* __restrict__ x, float* __restrict__ r, float* __restrict__ p,
    const float* __restrict__ Ap,
    const double* __restrict__ rr_src, int rr_is_slots,
    const double* __restrict__ paps, const double* __restrict__ raps,
    const double* __restrict__ apaps, double* __restrict__ rr_out,
    const int* __restrict__ zb, float* __restrict__ outp)
{
    __shared__ float sh_ab[2];
    int tid = threadIdx.x;
    if (tid < 64) {
        double v0 = rr_is_slots ? rr_src[tid * 32] : 0.0;
        double v1 = paps[tid * 32];
        double v2 = raps[tid * 32];
        double v3 = apaps[tid * 32];
        #pragma unroll
        for (int off = 32; off > 0; off >>= 1) {
            v0 += __shfl_down(v0, off, 64);
            v1 += __shfl_down(v1, off, 64);
            v2 += __shfl_down(v2, off, 64);
            v3 += __shfl_down(v3, off, 64);
        }
        if (tid == 0) {
            double rr_old = rr_is_slots ? v0 : rr_src[0];
            double alpha = rr_old / v1;
            double rr_new = rr_old - 2.0 * alpha * v2 + alpha * alpha * v3;
            if (blockIdx.x == 0) rr_out[0] = rr_new;
            sh_ab[0] = (float)alpha;
            sh_ab[1] = (float)(rr_new / rr_old);
        }
    }
    __syncthreads();
    float af = sh_ab[0], bf = sh_ab[1];

    int z = blockIdx.x >> 6;
    int i = blockIdx.x * 256 + tid;
    bool inslab = (z >= zb[0]) & (z <= zb[1]);
    if (!inslab) {
        if (outp) outp[i] = fmaxf(x[i], 0.0f);
        return;
    }
    float xv = fmaf(af, p[i], x[i]);
    x[i] = xv;
    float rvv = fmaf(-af, Ap[i], r[i]);
    r[i] = rvv;
    p[i] = fmaf(bf, p[i], rvv);
    if (outp) outp[i] = fmaxf(xv, 0.0f);
}

extern "C" void kernel_launch(void* const* d_in, const int* in_sizes, int n_in,
                              void* d_out, int out_size, void* d_ws, size_t ws_size,
                              hipStream_t stream) {
    const float* theta  = (const float*)d_in[0];  // [16,3,4]
    const float* slices = (const float*)d_in[1];  // [16,1,128,128]
    const float* volume = (const float*)d_in[2];  // [1,1,128,128,128]
    const float* psf    = (const float*)d_in[3];  // [3,3,3]
    float* out = (float*)d_out;

    char* ws = (char*)d_ws;
    float* x  = (float*)ws;
    float* r  = x  + VOX;     // r and p contiguous (single memset covers both)
    float* p  = r  + VOX;
    float* Ap = p  + VOX;
    float* sl = Ap + VOX;
    double* sc = (double*)(sl + NPIX);
    double* rrs0  = sc;             // 64 slots * stride 32 doubles (16 KB)
    double* paps  = sc + 2048;
    double* raps  = sc + 4096;
    double* apaps = sc + 6144;
    double* rr_sc = sc + 8192;      // rr chain scalars [0..10]
    float* cst = (float*)(sc + 8208);        // 16*128 floats + 9 globals
    int* zb = (int*)(cst + NS * CSTR + 16);  // [zlo, zhi]

    const int gapix = NPIX / 64;  // 4096 (a_kernel: 64-thread blocks)
    const int gvox = VOX / 256;   // 8192
    const int gat  = VOX / 512;   // 4096 (at_gather: 16x16x2 per block)

    prep_kernel<<<1, 512, 0, stream>>>(theta, psf, cst, zb);

    // x = volume; r = p = 0 (exact zeros outside written region)
    hipMemcpyAsync(x, volume, VOX * sizeof(float), hipMemcpyDeviceToDevice, stream);
    hipMemsetAsync(r, 0, 2 * VOX * sizeof(float), stream);

    // sl = slices - A(x0)   (a_kernel zeroes rrs0)
    a_kernel<<<gapix, 64, 0, stream>>>(cst, x, psf, sl, slices, rrs0, nullptr, nullptr);
    // r = p = At(sl) = b - AtA x0; rr0 = dot(r,r)
    at_gather_kernel<<<gat, 256, 0, stream>>>(cst, zb, sl, nullptr,
        nullptr, nullptr, rrs0, nullptr, nullptr, 1, r, p);

    for (int it = 0; it < 10; ++it) {
        // a_kernel zeroes the three dot-slot arrays (consumers done)
        a_kernel<<<gapix, 64, 0, stream>>>(cst, p, psf, sl, nullptr, paps, raps, apaps);
        at_gather_kernel<<<gat, 256, 0, stream>>>(cst, zb, sl, Ap,
            p, r, paps, raps, apaps, 0, nullptr, nullptr);

        const double* rr_src = (it == 0) ? rrs0 : &rr_sc[it];
        update_kernel<<<gvox, 256, 0, stream>>>(
            x, r, p, Ap, rr_src, (it == 0) ? 1 : 0,
            paps, raps, apaps, &rr_sc[it + 1], zb, (it == 9) ? out : nullptr);
    }
}

// Round 14
// 993.719 us; speedup vs baseline: 1.4947x; 1.4947x over previous
//
#include <hip/hip_runtime.h>
#include <math.h>

constexpr int VOX = 128 * 128 * 128;     // 2,097,152
constexpr int NPIX = 16 * 128 * 128;     // 262,144
constexpr int NS = 16;
constexpr float RES_RATIO = 1.5f;
constexpr int CSTR = 128;
// a_kernel LDS tile dims (provable bounds: x,y extent <= 18.1, z <= 8.1)
constexpr int TNX = 19, TNY = 19, TNZ = 10;

// Per-slice constant block (floats, stride 128):
//  [0..11]  T row-major  [12..14] tc=t+63.5  [15..17] col L1 norms
//  [18..20] row L1 norms [21..22] z slab     [24+3k..] rotated PSF offsets
// Globals at cst+NS*CSTR: separable psf fx[3],fy[3],fz[3] (1/c^2 in fz)

__global__ __launch_bounds__(512) void prep_kernel(
    const float* __restrict__ theta, const float* __restrict__ psf,
    float* __restrict__ cst, int* __restrict__ zb)
{
    int tid = threadIdx.x;
    int n = tid >> 5, j = tid & 31;
    if (n < NS) {
        const float* T = theta + n * 12;
        float* C = cst + n * CSTR;
        if (j < 12) C[j] = T[j];
        if (j == 12) {
            float r00=T[0], r01=T[1], r02=T[2],  t0=T[3];
            float r10=T[4], r11=T[5], r12=T[6],  t1=T[7];
            float r20=T[8], r21=T[9], r22=T[10], t2=T[11];
            float tc0 = t0 + 63.5f, tc1 = t1 + 63.5f, tc2 = t2 + 63.5f;
            C[12]=tc0; C[13]=tc1; C[14]=tc2;
            float C2 = fabsf(r02)+fabsf(r12)+fabsf(r22);
            C[15] = fabsf(r00)+fabsf(r10)+fabsf(r20);
            C[16] = fabsf(r01)+fabsf(r11)+fabsf(r21);
            C[17] = C2;
            C[18] = fabsf(r00)+fabsf(r01)+fabsf(r02);
            C[19] = fabsf(r10)+fabsf(r11)+fabsf(r12);
            C[20] = fabsf(r20)+fabsf(r21)+fabsf(r22);
            // conservative slab (covers at_scatter's widened per-column ranges)
            float mx = fmaxf(tc0, 127.0f - tc0);
            float my = fmaxf(tc1, 127.0f - tc1);
            float marg = 1.05f + C2 + fabsf(r02)*mx + fabsf(r12)*my;
            float inv = 1.0f / fabsf(r22);
            C[21] = tc2 - marg * inv;
            C[22] = tc2 + marg * inv;
        }
        if (j < 27) {
            float ox = (float)(j % 3) - 1.0f;
            float oy = (float)((j / 3) % 3) - 1.0f;
            float oz = (float)(j / 9) - 1.0f;
            C[24 + 3*j + 0] = T[0]*ox + T[1]*oy + T[2]*oz;
            C[24 + 3*j + 1] = T[4]*ox + T[5]*oy + T[6]*oz;
            C[24 + 3*j + 2] = T[8]*ox + T[9]*oy + T[10]*oz;
        }
    }
    __syncthreads();
    if (tid == 0) {
        float zmin = 1e30f, zmax = -1e30f;
        for (int s = 0; s < NS; ++s) {
            zmin = fminf(zmin, cst[s * CSTR + 21]);
            zmax = fmaxf(zmax, cst[s * CSTR + 22]);
        }
        zb[0] = max(0, (int)floorf(zmin));
        zb[1] = min(127, (int)ceilf(zmax));
        float* G = cst + NS * CSTR;
        float c = psf[13];
        float ic2 = 1.0f / (c * c);
        G[0]=psf[12]; G[1]=psf[13]; G[2]=psf[14];
        G[3]=psf[10]; G[4]=psf[13]; G[5]=psf[16];
        G[6]=psf[4]*ic2; G[7]=psf[13]*ic2; G[8]=psf[22]*ic2;
    }
}

// ---------------------------------------------------------------------------
// Reductions: 64 spread slots (stride 32 doubles). Contain __syncthreads():
// only block-uniform early returns may precede them.
// ---------------------------------------------------------------------------
__device__ __forceinline__ void block_reduce_spread(double s, double* slots)
{
    #pragma unroll
    for (int off = 32; off > 0; off >>= 1)
        s += __shfl_down(s, off, 64);
    __shared__ double ls[4];
    if ((threadIdx.x & 63) == 0) ls[threadIdx.x >> 6] = s;
    __syncthreads();
    if (threadIdx.x == 0)
        atomicAdd(&slots[(blockIdx.x & 63) * 32], ls[0] + ls[1] + ls[2] + ls[3]);
}

__device__ __forceinline__ void block_reduce3(
    double s0, double s1, double s2, double* a0, double* a1, double* a2)
{
    #pragma unroll
    for (int off = 32; off > 0; off >>= 1) {
        s0 += __shfl_down(s0, off, 64);
        s1 += __shfl_down(s1, off, 64);
        s2 += __shfl_down(s2, off, 64);
    }
    __shared__ double ls3[12];
    int wid = threadIdx.x >> 6;
    if ((threadIdx.x & 63) == 0) {
        ls3[wid*3+0] = s0; ls3[wid*3+1] = s1; ls3[wid*3+2] = s2;
    }
    __syncthreads();
    if (threadIdx.x == 0) {
        int sl = (blockIdx.x & 63) * 32;
        atomicAdd(&a0[sl], ls3[0]+ls3[3]+ls3[6]+ls3[9]);
        atomicAdd(&a1[sl], ls3[1]+ls3[4]+ls3[7]+ls3[10]);
        atomicAdd(&a2[sl], ls3[2]+ls3[5]+ls3[8]+ls3[11]);
    }
}

// ---------------------------------------------------------------------------
// A: PSF-weighted trilinear gather, LDS-tiled (64-thread blocks, 8x8 patch).
// If subsrc != null: out = subsrc - A(vol). Block 0 zeroes slot arrays.
// ---------------------------------------------------------------------------
__global__ __launch_bounds__(64) void a_kernel(
    const float* __restrict__ cst, const float* __restrict__ vol,
    const float* __restrict__ psf, float* __restrict__ out,
    const float* __restrict__ subsrc,
    double* __restrict__ z1, double* __restrict__ z2, double* __restrict__ z3)
{
    int tid = threadIdx.x;
    if (blockIdx.x == 0) {
        for (int i = tid; i < 2048; i += 64) {
            if (z1) z1[i] = 0.0;
            if (z2) z2[i] = 0.0;
            if (z3) z3[i] = 0.0;
        }
    }

    int b = blockIdx.x;              // 4096 blocks: n = b>>8, patch = b&255
    int n = b >> 8;
    int pb = b & 255;
    int w0 = (pb & 15) << 3, h0 = (pb >> 4) << 3;
    int w = w0 + (tid & 7), h = h0 + (tid >> 3);
    int oidx = (n << 14) + (h << 7) + w;
    float base = subsrc ? subsrc[oidx] : 0.0f;
    float sgn = subsrc ? -1.0f : 1.0f;

    const float* C = cst + n * CSTR;
    float r00=C[0], r01=C[1];
    float r10=C[4], r11=C[5];
    float r20=C[8], r21=C[9];

    float uc = (w0 + 3.5f - 63.5f) * RES_RATIO;
    float vc = (h0 + 3.5f - 63.5f) * RES_RATIO;
    const float du = 5.25f, dv = 5.25f;
    float cx = r00*uc + r01*vc + C[12];
    float cy = r10*uc + r11*vc + C[13];
    float cz = r20*uc + r21*vc + C[14];
    float hx = fabsf(r00)*du + fabsf(r01)*dv + C[18];
    float hy = fabsf(r10)*du + fabsf(r11)*dv + C[19];
    float hz = fabsf(r20)*du + fabsf(r21)*dv + C[20];
    int tx0 = (int)floorf(cx - hx);
    int ty0 = (int)floorf(cy - hy);
    int tz0 = (int)floorf(cz - hz);

    if (tx0 >= 128 || tx0 + TNX <= 0 || ty0 >= 128 || ty0 + TNY <= 0 ||
        tz0 >= 128 || tz0 + TNZ <= 0) {
        out[oidx] = base;
        return;
    }

    __shared__ float tile[TNZ * TNY * TNX];
    for (int i = tid; i < TNZ * TNY * TNX; i += 64) {
        int xx = i % TNX; int rem = i / TNX;
        int yy = rem % TNY; int zz = rem / TNY;
        int gx = tx0 + xx, gy = ty0 + yy, gz = tz0 + zz;
        bool ok = ((unsigned)gx < 128u) & ((unsigned)gy < 128u) & ((unsigned)gz < 128u);
        int off = ok ? ((gz << 14) + (gy << 7) + gx) : 0;
        float v = vol[off];
        tile[i] = ok ? v : 0.0f;
    }
    __syncthreads();

    float u = (w - 63.5f) * RES_RATIO;
    float v = (h - 63.5f) * RES_RATIO;
    float px = fmaf(r00, u, fmaf(r01, v, C[12])) - (float)tx0;
    float py = fmaf(r10, u, fmaf(r11, v, C[13])) - (float)ty0;
    float pz = fmaf(r20, u, fmaf(r21, v, C[14])) - (float)tz0;

    const float* O = C + 24;
    float acc = 0.0f;
    for (int k = 0; k < 27; ++k) {
        float sx = px + O[3*k+0];
        float sy = py + O[3*k+1];
        float sz = pz + O[3*k+2];
        int x0 = (int)sx, y0 = (int)sy, z0 = (int)sz;
        float fx = sx - (float)x0, fy = sy - (float)y0, fz = sz - (float)z0;
        const float* tp = tile + (z0 * TNY + y0) * TNX + x0;
        float c000 = tp[0],             c001 = tp[1];
        float c010 = tp[TNX],           c011 = tp[TNX+1];
        float c100 = tp[TNY*TNX],       c101 = tp[TNY*TNX+1];
        float c110 = tp[TNY*TNX+TNX],   c111 = tp[TNY*TNX+TNX+1];
        float c00 = fmaf(fx, c001 - c000, c000);
        float c01 = fmaf(fx, c011 - c010, c010);
        float c10 = fmaf(fx, c101 - c100, c100);
        float c11 = fmaf(fx, c111 - c110, c110);
        float c0  = fmaf(fy, c01 - c00, c00);
        float c1  = fmaf(fy, c11 - c10, c10);
        acc = fmaf(psf[k], fmaf(fz, c1 - c0, c0), acc);
    }
    out[oidx] = fmaf(sgn, acc, base);
}

// ---------------------------------------------------------------------------
// At, slice-major column walk with scatter: one thread per (x, y, slice n);
// n is block-uniform (scalar constants). The slice's active z interval per
// column is exact (gpz linear in z; +0.01 widening for fp safety — extra z
// produce exact zeros via clamped weights). One 4x4 sval register block per
// (column, slice): wb/hb drift over the <=4.9-z range is <=1 (2*|r20|*4.9<3),
// so the per-z 3-pixel window stays inside the block. Inner math = verified
// r7 shifted-lattice 5x5 with 4-way selects. Per-voxel results scatter via
// atomicAdd (~1.2M adds total; outvol must be pre-zeroed). No barriers.
// ---------------------------------------------------------------------------
__global__ __launch_bounds__(256) void at_scatter_kernel(
    const float* __restrict__ cst, const float* __restrict__ sl,
    float* __restrict__ outvol)
{
    int id = blockIdx.x * 256 + threadIdx.x;    // exact grid: NPIX threads
    int x = id & 127, y = (id >> 7) & 127, n = id >> 14;   // n block-uniform
    const float* C = cst + n * CSTR;
    float r00=C[0], r01=C[1], r02=C[2];
    float r10=C[4], r11=C[5], r12=C[6];
    float r20=C[8], r21=C[9], r22=C[10];
    float tc2 = C[14];
    float C0=C[15], C1=C[16], C2=C[17];

    float gx = (float)x - C[12];
    float gy = (float)y - C[13];

    // gpz(z) = az + r22*z ; active: |gpz| < 1 + C2 (+eps). r22 > 0 always.
    float az = r02*gx + r12*gy - r22*tc2;
    float lim = 1.0f + C2 + 0.01f;
    float inv22 = 1.0f / r22;
    int z0 = (int)ceilf((-lim - az) * inv22);
    int z1v = (int)floorf(( lim - az) * inv22);
    z0 = max(z0, 0); z1v = min(z1v, 127);
    if (z0 > z1v) return;                       // no barriers: safe

    float ax = r00*gx + r10*gy - r20*tc2;       // gpx = ax + r20*z
    float ay = r01*gx + r11*gy - r21*tc2;       // gpy = ay + r21*z

    // anchor pixel block from window extremes (monotone in z)
    float gpxa = fmaf(r20, (float)z0, ax), gpxb = fmaf(r20, (float)z1v, ax);
    float gpya = fmaf(r21, (float)z0, ay), gpyb = fmaf(r21, (float)z1v, ay);
    int m2a = (int)floorf(2.0f*(gpxa + 95.25f - C0)) + 601;
    int m2b = (int)floorf(2.0f*(gpxb + 95.25f - C0)) + 601;
    int n2a = (int)floorf(2.0f*(gpya + 95.25f - C1)) + 601;
    int n2b = (int)floorf(2.0f*(gpyb + 95.25f - C1)) + 601;
    int wb0 = min(m2a, m2b) / 3;                // biased by 200
    int hb0 = min(n2a, n2b) / 3;

    // 4x4 sval register block, OOB-masked
    const float* slice_n = sl + (n << 14);
    float s[4][4];
    #pragma unroll
    for (int aa = 0; aa < 4; ++aa) {
        int hv = hb0 - 200 + aa;
        bool hok = ((unsigned)hv < 128u);
        #pragma unroll
        for (int cc = 0; cc < 4; ++cc) {
            int wv = wb0 - 200 + cc;
            bool ok = hok & ((unsigned)wv < 128u);
            int off = ok ? ((hv << 7) + wv) : 0;
            float vs = slice_n[off];
            s[aa][cc] = ok ? vs : 0.0f;
        }
    }

    const float* G = cst + NS * CSTR;
    float pfx0=G[0], pfx1=G[1], pfx2=G[2];
    float pfy0=G[3], pfy1=G[4], pfy2=G[5];
    float pfz0=G[6], pfz1=G[7], pfz2=G[8];

    int yx = (y << 7) + x;

    for (int z = z0; z <= z1v; ++z) {
        float fzv = (float)z;
        float gpx = fmaf(r20, fzv, ax);
        float gpy = fmaf(r21, fzv, ay);
        float gz  = fzv - tc2;
        int m2 = (int)floorf(2.0f*(gpx + 95.25f - C0)) + 601;
        int n2 = (int)floorf(2.0f*(gpy + 95.25f - C1)) + 601;

        float fxv[5], cA[5], cB[5], cC[5], cD[5], Axa[5], Aya[5], Aza[5];
        #pragma unroll
        for (int i = 0; i < 5; ++i) {
            int m = m2 + i;
            int ki = m - (m / 3) * 3;
            int twoj = (ki == 0) ? 0 : ((ki == 1) ? -2 : 2);
            int wi = (m - twoj) / 3;
            int ci = wi - wb0;                   // 0..3
            fxv[i] = (ki == 0) ? pfx1 : ((ki == 1) ? pfx0 : pfx2);
            cA[i] = (ci==0)?s[0][0]:((ci==1)?s[0][1]:((ci==2)?s[0][2]:s[0][3]));
            cB[i] = (ci==0)?s[1][0]:((ci==1)?s[1][1]:((ci==2)?s[1][2]:s[1][3]));
            cC[i] = (ci==0)?s[2][0]:((ci==1)?s[2][1]:((ci==2)?s[2][2]:s[2][3]));
            cD[i] = (ci==0)?s[3][0]:((ci==1)?s[3][1]:((ci==2)?s[3][2]:s[3][3]));
            float mu = 0.5f * (float)(m - 600) - 95.25f;
            Axa[i] = fmaf(r00, mu, -gx);
            Aya[i] = fmaf(r10, mu, -gy);
            Aza[i] = fmaf(r20, mu, -gz);
        }
        float fyv[5], mvv[5];
        int rj[5];
        #pragma unroll
        for (int j = 0; j < 5; ++j) {
            int m = n2 + j;
            int kj = m - (m / 3) * 3;
            int twoj = (kj == 0) ? 0 : ((kj == 1) ? -2 : 2);
            int hj = (m - twoj) / 3;
            rj[j] = hj - hb0;                    // 0..3
            fyv[j] = (kj == 0) ? pfy1 : ((kj == 1) ? pfy0 : pfy2);
            mvv[j] = 0.5f * (float)(m - 600) - 95.25f;
        }

        float acc0 = 0.0f, acc1 = 0.0f;
        #pragma unroll
        for (int i = 0; i < 5; ++i) {
            #pragma unroll
            for (int j = 0; j < 5; ++j) {
                float sval = (rj[j]==0) ? cA[i]
                           : ((rj[j]==1) ? cB[i]
                           : ((rj[j]==2) ? cC[i] : cD[i]));
                float svf = sval * fxv[i] * fyv[j];
                float Bx = fmaf(r01, mvv[j], Axa[i]);
                float By = fmaf(r11, mvv[j], Aya[i]);
                float Bz = fmaf(r21, mvv[j], Aza[i]);
                float w0 = fmaxf(1.0f - fabsf(Bx - r02), 0.0f)
                         * fmaxf(1.0f - fabsf(By - r12), 0.0f)
                         * fmaxf(1.0f - fabsf(Bz - r22), 0.0f);
                float w1 = fmaxf(1.0f - fabsf(Bx), 0.0f)
                         * fmaxf(1.0f - fabsf(By), 0.0f)
                         * fmaxf(1.0f - fabsf(Bz), 0.0f);
                float w2 = fmaxf(1.0f - fabsf(Bx + r02), 0.0f)
                         * fmaxf(1.0f - fabsf(By + r12), 0.0f)
                         * fmaxf(1.0f - fabsf(Bz + r22), 0.0f);
                float t = fmaf(w0, pfz0, fmaf(w1, pfz1, w2 * pfz2));
                if (i & 1) acc1 = fmaf(t, svf, acc1);
                else       acc0 = fmaf(t, svf, acc0);
            }
        }
        atomicAdd(&outvol[(z << 14) + yx], acc0 + acc1);
    }
}

// p = r; Ap = 0; rr0 += r^2   [slab-skipped, block-uniform]
__global__ __launch_bounds__(256) void initpr_kernel(
    const float* __restrict__ r, float* __restrict__ p, float* __restrict__ Ap,
    double* __restrict__ rr_slots, const int* __restrict__ zb)
{
    int z = blockIdx.x >> 6;
    if (z < zb[0] || z > zb[1]) return;
    int i = blockIdx.x * 256 + threadIdx.x;
    float rv = r[i];
    p[i] = rv;
    Ap[i] = 0.0f;
    block_reduce_spread((double)rv * (double)rv, rr_slots);
}

// {pAp, rAp, ApAp} over the slab
__global__ __launch_bounds__(256) void dots_kernel(
    const float* __restrict__ Ap, const float* __restrict__ p,
    const float* __restrict__ r,
    double* __restrict__ s_pap, double* __restrict__ s_rap,
    double* __restrict__ s_apap, const int* __restrict__ zb)
{
    int z = blockIdx.x >> 6;
    if (z < zb[0] || z > zb[1]) return;
    int i = blockIdx.x * 256 + threadIdx.x;
    double a = (double)Ap[i];
    block_reduce3(a * (double)p[i], a * (double)r[i], a * a,
                  s_pap, s_rap, s_apap);
}

// ---------------------------------------------------------------------------
// Merged CG update: alpha = rr_old/pAp; rr_new = rr_old - 2a*rAp + a^2*ApAp;
// beta = rr_new/rr_old; x += a p; r -= a Ap; p = r + beta p; Ap = 0 (for the
// next iteration's scatter).
// ---------------------------------------------------------------------------
__global__ __launch_bounds__(256) void update_kernel(
    float* __restrict__ x, float* __restrict__ r, float* __restrict__ p,
    float* __restrict__ Ap,
    const double* __restrict__ rr_src, int rr_is_slots,
    const double* __restrict__ paps, const double* __restrict__ raps,
    const double* __restrict__ apaps, double* __restrict__ rr_out,
    const int* __restrict__ zb, float* __restrict__ outp)
{
    __shared__ float sh_ab[2];
    int tid = threadIdx.x;
    if (tid < 64) {
        double v0 = rr_is_slots ? rr_src[tid * 32] : 0.0;
        double v1 = paps[tid * 32];
        double v2 = raps[tid * 32];
        double v3 = apaps[tid * 32];
        #pragma unroll
        for (int off = 32; off > 0; off >>= 1) {
            v0 += __shfl_down(v0, off, 64);
            v1 += __shfl_down(v1, off, 64);
            v2 += __shfl_down(v2, off, 64);
            v3 += __shfl_down(v3, off, 64);
        }
        if (tid == 0) {
            double rr_old = rr_is_slots ? v0 : rr_src[0];
            double alpha = rr_old / v1;
            double rr_new = rr_old - 2.0 * alpha * v2 + alpha * alpha * v3;
            if (blockIdx.x == 0) rr_out[0] = rr_new;
            sh_ab[0] = (float)alpha;
            sh_ab[1] = (float)(rr_new / rr_old);
        }
    }
    __syncthreads();
    float af = sh_ab[0], bf = sh_ab[1];

    int z = blockIdx.x >> 6;
    int i = blockIdx.x * 256 + tid;
    bool inslab = (z >= zb[0]) & (z <= zb[1]);
    if (!inslab) {
        if (outp) outp[i] = fmaxf(x[i], 0.0f);
        return;
    }
    float xv = fmaf(af, p[i], x[i]);
    x[i] = xv;
    float apv = Ap[i];
    Ap[i] = 0.0f;
    float rvv = fmaf(-af, apv, r[i]);
    r[i] = rvv;
    p[i] = fmaf(bf, p[i], rvv);
    if (outp) outp[i] = fmaxf(xv, 0.0f);
}

extern "C" void kernel_launch(void* const* d_in, const int* in_sizes, int n_in,
                              void* d_out, int out_size, void* d_ws, size_t ws_size,
                              hipStream_t stream) {
    const float* theta  = (const float*)d_in[0];  // [16,3,4]
    const float* slices = (const float*)d_in[1];  // [16,1,128,128]
    const float* volume = (const float*)d_in[2];  // [1,1,128,128,128]
    const float* psf    = (const float*)d_in[3];  // [3,3,3]
    float* out = (float*)d_out;

    char* ws = (char*)d_ws;
    float* x  = (float*)ws;
    float* r  = x  + VOX;     // r and p contiguous (single memset covers both)
    float* p  = r  + VOX;
    float* Ap = p  + VOX;
    float* sl = Ap + VOX;
    double* sc = (double*)(sl + NPIX);
    double* rrs0  = sc;             // 64 slots * stride 32 doubles (16 KB)
    double* paps  = sc + 2048;
    double* raps  = sc + 4096;
    double* apaps = sc + 6144;
    double* rr_sc = sc + 8192;      // rr chain scalars [0..10]
    float* cst = (float*)(sc + 8208);        // 16*128 floats + 9 globals
    int* zb = (int*)(cst + NS * CSTR + 16);  // [zlo, zhi]

    const int gapix = NPIX / 64;  // 4096 (a_kernel: 64-thread blocks)
    const int gvox = VOX / 256;   // 8192
    const int gsc  = NPIX / 256;  // 1024 (at_scatter: thread per (x,y,n))

    prep_kernel<<<1, 512, 0, stream>>>(theta, psf, cst, zb);

    // x = volume; r = p = 0 (exact zeros; r is at_scatter's first target)
    hipMemcpyAsync(x, volume, VOX * sizeof(float), hipMemcpyDeviceToDevice, stream);
    hipMemsetAsync(r, 0, 2 * VOX * sizeof(float), stream);

    // sl = slices - A(x0)   (a_kernel zeroes rrs0)
    a_kernel<<<gapix, 64, 0, stream>>>(cst, x, psf, sl, slices, rrs0, nullptr, nullptr);
    // r += At(sl) = b - AtA x0  (scatter into zeroed r)
    at_scatter_kernel<<<gsc, 256, 0, stream>>>(cst, sl, r);
    // p = r; Ap = 0; rr0 = dot(r,r)
    initpr_kernel<<<gvox, 256, 0, stream>>>(r, p, Ap, rrs0, zb);

    for (int it = 0; it < 10; ++it) {
        // a_kernel zeroes the three dot-slot arrays (consumers done)
        a_kernel<<<gapix, 64, 0, stream>>>(cst, p, psf, sl, nullptr, paps, raps, apaps);
        // Ap += At(A p)   (Ap zeroed by initpr / previous update)
        at_scatter_kernel<<<gsc, 256, 0, stream>>>(cst, sl, Ap);
        // {pAp, rAp, ApAp}
        dots_kernel<<<gvox, 256, 0, stream>>>(Ap, p, r, paps, raps, apaps, zb);

        const double* rr_src = (it == 0) ? rrs0 : &rr_sc[it];
        update_kernel<<<gvox, 256, 0, stream>>>(
            x, r, p, Ap, rr_src, (it == 0) ? 1 : 0,
            paps, raps, apaps, &rr_sc[it + 1], zb, (it == 9) ? out : nullptr);
    }
}